// Round 7
// baseline (440.216 us; speedup 1.0000x reference)
//
#include <hip/hip_runtime.h>

typedef __bf16 bf16_t;
typedef __bf16 bf16x8 __attribute__((ext_vector_type(8)));
typedef __bf16 bf16x4 __attribute__((ext_vector_type(4)));
typedef float f32x4 __attribute__((ext_vector_type(4)));

#define MFMA16(a, b, c) __builtin_amdgcn_mfma_f32_16x16x32_bf16((a), (b), (c), 0, 0, 0)

__device__ __forceinline__ void gload_lds16(const void* g, void* l) {
  __builtin_amdgcn_global_load_lds(
      (__attribute__((address_space(1))) void*)(g),
      (__attribute__((address_space(3))) void*)(l), 16, 0, 0);
}

__device__ __forceinline__ void block_bar() {
  asm volatile("" ::: "memory");
  __builtin_amdgcn_s_barrier();
  asm volatile("" ::: "memory");
}

// ---------------- fp32 -> bf16 conversion ----------------
__global__ __launch_bounds__(256) void cvt_f32_bf16(const float* __restrict__ in,
                                                    bf16_t* __restrict__ out, int n4) {
  int i = blockIdx.x * 256 + threadIdx.x;
  if (i >= n4) return;
  float4 v = ((const float4*)in)[i];
  bf16x4 o;
  o[0] = (bf16_t)v.x; o[1] = (bf16_t)v.y; o[2] = (bf16_t)v.z; o[3] = (bf16_t)v.w;
  ((bf16x4*)out)[i] = o;
}

// ---------------- 256x256 8-phase bf16 GEMM (QKV), C = A * Bw^T + bias ----------------
// T2 chunk-XOR swizzle (pre-swizzled global source, swizzled ds_read) +
// T3/T4 phase interleave with one counted wait per K-tile + T5 setprio.
// 8 waves (2M x 4N), wave tile 128x64, BK=64, LDS 128 KiB double-buffered.
// Epilogue scatters Q (scaled), K (head-major), V^T (d-major) in bf16.
__global__ __launch_bounds__(512) void gemm_qkv_256(
    const bf16_t* __restrict__ A, const bf16_t* __restrict__ Bw,
    const float* __restrict__ bias,
    bf16_t* __restrict__ qb, bf16_t* __restrict__ kb, bf16_t* __restrict__ vtb,
    int M, int N, int K) {
  __shared__ __attribute__((aligned(16))) bf16_t As[2][256][64];
  __shared__ __attribute__((aligned(16))) bf16_t Bs[2][256][64];
  const int tid = threadIdx.x;
  const int lane = tid & 63;
  const int w = tid >> 6;            // 0..7
  const int wm = w >> 2, wn = w & 3; // 2 x 4 wave grid
  const int l15 = lane & 15, l4 = lane >> 4;
  const int bm = blockIdx.y * 256, bn = blockIdx.x * 256;

  f32x4 acc[8][4];
#pragma unroll
  for (int i = 0; i < 8; ++i)
#pragma unroll
    for (int j = 0; j < 4; ++j)
#pragma unroll
      for (int r = 0; r < 4; ++r) acc[i][j][r] = 0.0f;

  // staging mapping: 512 threads -> 64 rows x 8 chunks(16B) per 8KB load-round
  const int srow = tid >> 3;   // 0..63
  const int schk = tid & 7;    // 0..7

  // linear LDS dest, inverse-swizzled global source (involution: chunk ^ (row&7))
  auto stageA = [&](int q, int ti, int i) {
    int r = (i << 6) + srow;
    int cl = (schk ^ (r & 7)) << 3;  // element offset of 16B chunk
    gload_lds16(A + (size_t)(bm + r) * K + (ti << 6) + cl, &As[q][r][schk << 3]);
  };
  auto stageB = [&](int q, int ti, int i) {
    int r = (i << 6) + srow;
    int cl = (schk ^ (r & 7)) << 3;
    gload_lds16(Bw + (size_t)(bn + r) * K + (ti << 6) + cl, &Bs[q][r][schk << 3]);
  };
  // swizzled fragment reads (2-way bank aliasing per quarter-wave = free)
  auto afrag = [&](int p, int mf, int ks) -> bf16x8 {
    int row = wm * 128 + mf * 16 + l15;
    int ch = ((ks << 2) | l4) ^ (row & 7);
    return *(const bf16x8*)(&As[p][row][ch << 3]);
  };
  auto bfrag = [&](int p, int nf, int ks) -> bf16x8 {
    int row = wn * 64 + nf * 16 + l15;
    int ch = ((ks << 2) | l4) ^ (row & 7);
    return *(const bf16x8*)(&Bs[p][row][ch << 3]);
  };

  const int nt = K >> 6;  // K-tiles of 64

  // prologue: stage tile 0 into buf 0
#pragma unroll
  for (int i = 0; i < 4; ++i) stageA(0, 0, i);
#pragma unroll
  for (int i = 0; i < 4; ++i) stageB(0, 0, i);

  bf16x8 afr[4], bfr[4];

#pragma unroll 1
  for (int t = 0; t < nt; ++t) {
    const int p = t & 1, q = p ^ 1;
    const bool pf = (t + 1 < nt);
    // tile t's 8 loads (issued across tile t-1's phases) must be in LDS
    asm volatile("s_waitcnt vmcnt(0)" ::: "memory");
    block_bar();

    // ---- phase 0: mf 0-3, ks 0; stage A halves 0,1 of tile t+1 ----
#pragma unroll
    for (int n = 0; n < 4; ++n) bfr[n] = bfrag(p, n, 0);
#pragma unroll
    for (int j = 0; j < 4; ++j) afr[j] = afrag(p, j, 0);
    if (pf) { stageA(q, t + 1, 0); stageA(q, t + 1, 1); }
    block_bar();
    __builtin_amdgcn_s_setprio(1);
#pragma unroll
    for (int j = 0; j < 4; ++j)
#pragma unroll
      for (int n = 0; n < 4; ++n) acc[j][n] = MFMA16(afr[j], bfr[n], acc[j][n]);
    __builtin_amdgcn_s_setprio(0);
    block_bar();

    // ---- phase 1: mf 4-7, ks 0; stage A halves 2,3 ----
#pragma unroll
    for (int j = 0; j < 4; ++j) afr[j] = afrag(p, 4 + j, 0);
    if (pf) { stageA(q, t + 1, 2); stageA(q, t + 1, 3); }
    block_bar();
    __builtin_amdgcn_s_setprio(1);
#pragma unroll
    for (int j = 0; j < 4; ++j)
#pragma unroll
      for (int n = 0; n < 4; ++n) acc[4 + j][n] = MFMA16(afr[j], bfr[n], acc[4 + j][n]);
    __builtin_amdgcn_s_setprio(0);
    block_bar();

    // ---- phase 2: mf 0-3, ks 1; stage B halves 0,1 ----
#pragma unroll
    for (int n = 0; n < 4; ++n) bfr[n] = bfrag(p, n, 1);
#pragma unroll
    for (int j = 0; j < 4; ++j) afr[j] = afrag(p, j, 1);
    if (pf) { stageB(q, t + 1, 0); stageB(q, t + 1, 1); }
    block_bar();
    __builtin_amdgcn_s_setprio(1);
#pragma unroll
    for (int j = 0; j < 4; ++j)
#pragma unroll
      for (int n = 0; n < 4; ++n) acc[j][n] = MFMA16(afr[j], bfr[n], acc[j][n]);
    __builtin_amdgcn_s_setprio(0);
    block_bar();

    // ---- phase 3: mf 4-7, ks 1; stage B halves 2,3 ----
#pragma unroll
    for (int j = 0; j < 4; ++j) afr[j] = afrag(p, 4 + j, 1);
    if (pf) { stageB(q, t + 1, 2); stageB(q, t + 1, 3); }
    block_bar();
    __builtin_amdgcn_s_setprio(1);
#pragma unroll
    for (int j = 0; j < 4; ++j)
#pragma unroll
      for (int n = 0; n < 4; ++n) acc[4 + j][n] = MFMA16(afr[j], bfr[n], acc[4 + j][n]);
    __builtin_amdgcn_s_setprio(0);
    block_bar();
  }

  // epilogue: scatter to Q (scaled), K, V^T
  const int which = bn >> 11;          // uniform per block (2048 % 256 == 0)
#pragma unroll
  for (int mf = 0; mf < 8; ++mf)
#pragma unroll
    for (int nf = 0; nf < 4; ++nf)
#pragma unroll
      for (int r = 0; r < 4; ++r) {
        int m = bm + wm * 128 + mf * 16 + l4 * 4 + r;
        int n = bn + wn * 64 + nf * 16 + l15;
        float v = acc[mf][nf][r] + bias[n];
        int b = m >> 11, s = m & 2047;
        int d = n & 127;
        int head = (n & 2047) >> 7;
        size_t hb = (size_t)(b * 16 + head);
        if (which == 0) {
          v *= 0.08838834764831845f;  // 1/sqrt(128)
          qb[(hb * 2048 + s) * 128 + d] = (bf16_t)v;
        } else if (which == 1) {
          kb[(hb * 2048 + s) * 128 + d] = (bf16_t)v;
        } else {
          vtb[(hb * 128 + d) * 2048 + s] = (bf16_t)v;
        }
      }
}

// ---------------- bf16 GEMM, C = A * Bw^T (+bias fp32 out), 128x128 tile ----------------
// 2-phase counted-vmcnt double-buffer (R6 structure) — used for the dense proj.
__global__ __launch_bounds__(256) void gemm_bt_dense(
    const bf16_t* __restrict__ A, const bf16_t* __restrict__ Bw,
    const float* __restrict__ bias, float* __restrict__ O,
    int M, int N, int K) {
  __shared__ __attribute__((aligned(16))) bf16_t As[2][128][32];
  __shared__ __attribute__((aligned(16))) bf16_t Bs[2][128][32];
  const int tid = threadIdx.x;
  const int lane = tid & 63, wave = tid >> 6;
  const int wr = (wave >> 1) * 64, wc = (wave & 1) * 64;
  const int l15 = lane & 15, l4 = lane >> 4;
  const int bm = blockIdx.y * 128, bn = blockIdx.x * 128;

  f32x4 acc[4][4];
#pragma unroll
  for (int i = 0; i < 4; ++i)
#pragma unroll
    for (int j = 0; j < 4; ++j)
#pragma unroll
      for (int r = 0; r < 4; ++r) acc[i][j][r] = 0.0f;

  const int r0 = tid >> 2;
  const int co = (tid & 3) * 8;
  const bf16_t* gA = A + (size_t)(bm + r0) * K + co;
  const bf16_t* gB = Bw + (size_t)(bn + r0) * K + co;

  const int nt = K >> 5;

  gload_lds16(gA, &As[0][r0][co]);
  gload_lds16(gA + (size_t)64 * K, &As[0][r0 + 64][co]);
  gload_lds16(gB, &Bs[0][r0][co]);
  gload_lds16(gB + (size_t)64 * K, &Bs[0][r0 + 64][co]);

#pragma unroll 1
  for (int t = 0; t < nt; ++t) {
    const int cb = t & 1;
    if (t + 1 < nt) {
      const int kk = (t + 1) << 5;
      const int nb = cb ^ 1;
      gload_lds16(gA + kk, &As[nb][r0][co]);
      gload_lds16(gA + kk + (size_t)64 * K, &As[nb][r0 + 64][co]);
      gload_lds16(gB + kk, &Bs[nb][r0][co]);
      gload_lds16(gB + kk + (size_t)64 * K, &Bs[nb][r0 + 64][co]);
      asm volatile("s_waitcnt vmcnt(4)" ::: "memory");
    } else {
      asm volatile("s_waitcnt vmcnt(0)" ::: "memory");
    }
    block_bar();
    bf16x8 a[4], b[4];
#pragma unroll
    for (int i = 0; i < 4; ++i) a[i] = *(const bf16x8*)(&As[cb][wr + i * 16 + l15][l4 * 8]);
#pragma unroll
    for (int j = 0; j < 4; ++j) b[j] = *(const bf16x8*)(&Bs[cb][wc + j * 16 + l15][l4 * 8]);
#pragma unroll
    for (int i = 0; i < 4; ++i)
#pragma unroll
      for (int j = 0; j < 4; ++j) acc[i][j] = MFMA16(a[i], b[j], acc[i][j]);
    block_bar();
  }

#pragma unroll
  for (int i = 0; i < 4; ++i)
#pragma unroll
    for (int j = 0; j < 4; ++j)
#pragma unroll
      for (int r = 0; r < 4; ++r) {
        int m = bm + wr + i * 16 + l4 * 4 + r;
        int n = bn + wc + j * 16 + l15;
        O[(size_t)m * N + n] = acc[i][j][r] + bias[n];
      }
}

// ---------------- causal flash attention (R5-verified) ----------------
__global__ __launch_bounds__(512) void attn_kernel(
    const bf16_t* __restrict__ qbuf, const bf16_t* __restrict__ kbuf,
    const bf16_t* __restrict__ vtbuf, bf16_t* __restrict__ ctx) {
  __shared__ __attribute__((aligned(16))) bf16_t Ks[2][64][128];
  __shared__ __attribute__((aligned(16))) bf16_t Vts[2][128][64];
  __shared__ __attribute__((aligned(16))) bf16_t Ps[8][16][64];

  const int tid = threadIdx.x, lane = tid & 63, w = tid >> 6;
  const int l15 = lane & 15, l4 = lane >> 4;
  const int hb = blockIdx.y;
  const size_t hoff = (size_t)hb * 2048 * 128;
  const bf16_t* qh = qbuf + hoff;
  const bf16_t* kh = kbuf + hoff;
  const bf16_t* vh = vtbuf + hoff;
  const int b = hb >> 4, head = hb & 15;

  const int kr0 = tid >> 4, ks0 = tid & 15;
  const int vr0 = tid >> 3, vs0 = tid & 7;

  int buf = 0;

#pragma unroll 1
  for (int phase = 0; phase < 2; ++phase) {
    const int qt = phase == 0 ? blockIdx.x : 15 - blockIdx.x;
    const int q0 = qt * 128;
    const int nt = 2 * qt + 2;

    bf16x8 qa[4];
#pragma unroll
    for (int ks = 0; ks < 4; ++ks)
      qa[ks] = *(const bf16x8*)(qh + (size_t)(q0 + w * 16 + l15) * 128 + ks * 32 + l4 * 8);

    f32x4 accO[8];
#pragma unroll
    for (int df = 0; df < 8; ++df)
#pragma unroll
      for (int r = 0; r < 4; ++r) accO[df][r] = 0.0f;
    float mrow[4], lrow[4];
#pragma unroll
    for (int r = 0; r < 4; ++r) { mrow[r] = -1e30f; lrow[r] = 0.0f; }

    {
      const int kv0 = 0;
#pragma unroll
      for (int it = 0; it < 2; ++it) {
        int row = kr0 + it * 32, sch = ks0 ^ (row & 7);
        gload_lds16(kh + (size_t)(kv0 + row) * 128 + sch * 8, &Ks[buf][row][ks0 * 8]);
      }
#pragma unroll
      for (int it = 0; it < 2; ++it) {
        int row = vr0 + it * 64, sch = vs0 ^ (row & 7);
        gload_lds16(vh + (size_t)row * 2048 + kv0 + sch * 8, &Vts[buf][row][vs0 * 8]);
      }
    }

#pragma unroll 1
    for (int t = 0; t < nt; ++t) {
      const int kv0 = t * 64;
      if (t + 1 < nt) {
        const int kvn = (t + 1) * 64;
        const int nb = buf ^ 1;
#pragma unroll
        for (int it = 0; it < 2; ++it) {
          int row = kr0 + it * 32, sch = ks0 ^ (row & 7);
          gload_lds16(kh + (size_t)(kvn + row) * 128 + sch * 8, &Ks[nb][row][ks0 * 8]);
        }
#pragma unroll
        for (int it = 0; it < 2; ++it) {
          int row = vr0 + it * 64, sch = vs0 ^ (row & 7);
          gload_lds16(vh + (size_t)row * 2048 + kvn + sch * 8, &Vts[nb][row][vs0 * 8]);
        }
        asm volatile("s_waitcnt vmcnt(4)" ::: "memory");
      } else {
        asm volatile("s_waitcnt vmcnt(0)" ::: "memory");
      }
      block_bar();

      const bool active = (kv0 <= q0 + w * 16 + 15);
      if (active) {
        f32x4 sc[4];
#pragma unroll
        for (int nf = 0; nf < 4; ++nf) {
#pragma unroll
          for (int r = 0; r < 4; ++r) sc[nf][r] = 0.0f;
          int row = nf * 16 + l15;
#pragma unroll
          for (int ks = 0; ks < 4; ++ks) {
            int ch = (ks * 4 + l4) ^ (row & 7);
            bf16x8 kf = *(const bf16x8*)(&Ks[buf][row][ch * 8]);
            sc[nf] = MFMA16(qa[ks], kf, sc[nf]);
          }
        }

        if (kv0 + 63 > q0 + w * 16) {
#pragma unroll
          for (int nf = 0; nf < 4; ++nf)
#pragma unroll
            for (int r = 0; r < 4; ++r) {
              int qi = q0 + w * 16 + l4 * 4 + r;
              int kv = kv0 + nf * 16 + l15;
              if (kv > qi) sc[nf][r] = -1e30f;
            }
        }

        float tmax[4];
#pragma unroll
        for (int r = 0; r < 4; ++r)
          tmax[r] = fmaxf(fmaxf(sc[0][r], sc[1][r]), fmaxf(sc[2][r], sc[3][r]));
#pragma unroll
        for (int msk = 1; msk <= 8; msk <<= 1)
#pragma unroll
          for (int r = 0; r < 4; ++r)
            tmax[r] = fmaxf(tmax[r], __shfl_xor(tmax[r], msk, 64));

        bool defer = __all(tmax[0] <= mrow[0] + 8.0f && tmax[1] <= mrow[1] + 8.0f &&
                           tmax[2] <= mrow[2] + 8.0f && tmax[3] <= mrow[3] + 8.0f);
        if (!defer) {
          float scl[4];
#pragma unroll
          for (int r = 0; r < 4; ++r) {
            float mn = fmaxf(mrow[r], tmax[r]);
            scl[r] = __expf(mrow[r] - mn);
            mrow[r] = mn;
            lrow[r] *= scl[r];
          }
#pragma unroll
          for (int df = 0; df < 8; ++df)
#pragma unroll
            for (int r = 0; r < 4; ++r) accO[df][r] *= scl[r];
        }

        float rsum[4];
#pragma unroll
        for (int r = 0; r < 4; ++r) {
          float s0 = 0.0f;
#pragma unroll
          for (int nf = 0; nf < 4; ++nf) {
            float p = __expf(sc[nf][r] - mrow[r]);
            sc[nf][r] = p;
            s0 += p;
          }
          rsum[r] = s0;
        }
#pragma unroll
        for (int msk = 1; msk <= 8; msk <<= 1)
#pragma unroll
          for (int r = 0; r < 4; ++r) rsum[r] += __shfl_xor(rsum[r], msk, 64);
#pragma unroll
        for (int r = 0; r < 4; ++r) lrow[r] += rsum[r];

#pragma unroll
        for (int nf = 0; nf < 4; ++nf)
#pragma unroll
          for (int r = 0; r < 4; ++r) {
            int qi = l4 * 4 + r;
            int kv = nf * 16 + l15;
            int ch = (kv >> 3) ^ (qi & 7);
            Ps[w][qi][ch * 8 + (kv & 7)] = (bf16_t)sc[nf][r];
          }

        bf16x8 pa[2];
#pragma unroll
        for (int k2 = 0; k2 < 2; ++k2) {
          int ch = (k2 * 4 + l4) ^ (l15 & 7);
          pa[k2] = *(const bf16x8*)(&Ps[w][l15][ch * 8]);
        }
#pragma unroll
        for (int df = 0; df < 8; ++df) {
          int row = df * 16 + l15;
#pragma unroll
          for (int k2 = 0; k2 < 2; ++k2) {
            int ch = (k2 * 4 + l4) ^ (row & 7);
            bf16x8 vf = *(const bf16x8*)(&Vts[buf][row][ch * 8]);
            accO[df] = MFMA16(pa[k2], vf, accO[df]);
          }
        }
      }
      block_bar();
      buf ^= 1;
    }

    float inv[4];
#pragma unroll
    for (int r = 0; r < 4; ++r) inv[r] = 1.0f / lrow[r];
#pragma unroll
    for (int df = 0; df < 8; ++df)
#pragma unroll
      for (int r = 0; r < 4; ++r) {
        int s = q0 + w * 16 + l4 * 4 + r;
        int col = head * 128 + df * 16 + l15;
        ctx[((size_t)(b * 2048 + s)) * 2048 + col] = (bf16_t)(accO[df][r] * inv[r]);
      }
  }
}

extern "C" void kernel_launch(void* const* d_in, const int* in_sizes, int n_in,
                              void* d_out, int out_size, void* d_ws, size_t ws_size,
                              hipStream_t stream) {
  const float* hs = (const float*)d_in[0];
  const float* w_qkv = (const float*)d_in[2];
  const float* b_qkv = (const float*)d_in[3];
  const float* w_dense = (const float*)d_in[4];
  const float* b_dense = (const float*)d_in[5];
  float* out = (float*)d_out;

  const size_t SZ_HS = (size_t)4096 * 2048;
  const size_t SZ_WQKV = (size_t)6144 * 2048;
  const size_t SZ_WD = (size_t)2048 * 2048;
  const size_t SZ_H = (size_t)32 * 2048 * 128;

  char* ws = (char*)d_ws;
  bf16_t* A_ = (bf16_t*)ws;
  bf16_t* B_ = (bf16_t*)(ws + 2 * SZ_HS);
  bf16_t* Q_ = (bf16_t*)(ws + 2 * (SZ_HS + SZ_WQKV));
  bf16_t* K_ = Q_ + SZ_H;
  bf16_t* V_ = K_ + SZ_H;

  cvt_f32_bf16<<<(int)(SZ_HS / 4 / 256), 256, 0, stream>>>(hs, A_, (int)(SZ_HS / 4));
  cvt_f32_bf16<<<(int)(SZ_WQKV / 4 / 256), 256, 0, stream>>>(w_qkv, B_, (int)(SZ_WQKV / 4));

  gemm_qkv_256<<<dim3(24, 16), 512, 0, stream>>>(A_, B_, b_qkv, Q_, K_, V_, 4096, 6144, 2048);

  cvt_f32_bf16<<<(int)(SZ_WD / 4 / 256), 256, 0, stream>>>(w_dense, A_, (int)(SZ_WD / 4));

  attn_kernel<<<dim3(8, 32), 512, 0, stream>>>(Q_, K_, V_, B_);

  gemm_bt_dense<<<dim3(16, 32), 256, 0, stream>>>(B_, A_, b_dense, out, 4096, 2048, 2048);
}

// Round 8
// 431.406 us; speedup vs baseline: 1.0204x; 1.0204x over previous
//
#include <hip/hip_runtime.h>

typedef __bf16 bf16_t;
typedef __bf16 bf16x8 __attribute__((ext_vector_type(8)));
typedef __bf16 bf16x4 __attribute__((ext_vector_type(4)));
typedef float f32x4 __attribute__((ext_vector_type(4)));

#define MFMA16(a, b, c) __builtin_amdgcn_mfma_f32_16x16x32_bf16((a), (b), (c), 0, 0, 0)

__device__ __forceinline__ void gload_lds16(const void* g, void* l) {
  __builtin_amdgcn_global_load_lds(
      (__attribute__((address_space(1))) void*)(g),
      (__attribute__((address_space(3))) void*)(l), 16, 0, 0);
}

__device__ __forceinline__ void block_bar() {
  asm volatile("" ::: "memory");
  __builtin_amdgcn_s_barrier();
  asm volatile("" ::: "memory");
}

// ---------------- fp32 -> bf16 conversion ----------------
__global__ __launch_bounds__(256) void cvt_f32_bf16(const float* __restrict__ in,
                                                    bf16_t* __restrict__ out, int n4) {
  int i = blockIdx.x * 256 + threadIdx.x;
  if (i >= n4) return;
  float4 v = ((const float4*)in)[i];
  bf16x4 o;
  o[0] = (bf16_t)v.x; o[1] = (bf16_t)v.y; o[2] = (bf16_t)v.z; o[3] = (bf16_t)v.w;
  ((bf16x4*)out)[i] = o;
}

// ---------------- 256x256 bf16 GEMM (QKV), BK=32, triple-buffer lead-2 ----------------
// Counted vmcnt (T4): tile t+2 staged during tile t -> vmcnt(4) at tile top keeps
// tile t+1's 4 loads in flight across barriers; no mid-loop drain.
// T2 chunk-XOR swizzle (involution chunk^(row&3), 64B rows), T5 setprio.
// 8 waves (2M x 4N), wave tile 128x64. LDS 96 KiB (3 slots x (A 16K + B 16K)).
__global__ __launch_bounds__(512) void gemm_qkv_256(
    const bf16_t* __restrict__ A, const bf16_t* __restrict__ Bw,
    const float* __restrict__ bias,
    bf16_t* __restrict__ qb, bf16_t* __restrict__ kb, bf16_t* __restrict__ vtb,
    int M, int N, int K) {
  __shared__ __attribute__((aligned(16))) bf16_t As[3][256][32];
  __shared__ __attribute__((aligned(16))) bf16_t Bs[3][256][32];
  const int tid = threadIdx.x;
  const int lane = tid & 63;
  const int w = tid >> 6;            // 0..7
  const int wm = w >> 2, wn = w & 3; // 2 x 4 wave grid
  const int l15 = lane & 15, l4 = lane >> 4;
  const int bm = blockIdx.y * 256, bn = blockIdx.x * 256;

  f32x4 acc[8][4];
#pragma unroll
  for (int i = 0; i < 8; ++i)
#pragma unroll
    for (int j = 0; j < 4; ++j)
#pragma unroll
      for (int r = 0; r < 4; ++r) acc[i][j][r] = 0.0f;

  // staging: 512 threads; per call = 128 rows x 32 cols (8KB). 2 calls per operand.
  const int srow = tid >> 2;   // 0..127
  const int schk = tid & 3;    // 0..3 (16B chunks in a 64B row)

  // linear LDS dest (addr = tid*16 within the 8KB block), inverse-swizzled source
  auto stageA = [&](int q, int ti, int i) {
    int r = (i << 7) + srow;
    int cl = (schk ^ (r & 3)) << 3;
    gload_lds16(A + (size_t)(bm + r) * K + (ti << 5) + cl, &As[q][r][schk << 3]);
  };
  auto stageB = [&](int q, int ti, int i) {
    int r = (i << 7) + srow;
    int cl = (schk ^ (r & 3)) << 3;
    gload_lds16(Bw + (size_t)(bn + r) * K + (ti << 5) + cl, &Bs[q][r][schk << 3]);
  };
  // swizzled fragment reads: one b128 covers the lane's full K=32 fragment
  auto afrag = [&](int p, int mf) -> bf16x8 {
    int row = wm * 128 + mf * 16 + l15;
    int ch = l4 ^ (row & 3);
    return *(const bf16x8*)(&As[p][row][ch << 3]);
  };
  auto bfrag = [&](int p, int nf) -> bf16x8 {
    int row = wn * 64 + nf * 16 + l15;
    int ch = l4 ^ (row & 3);
    return *(const bf16x8*)(&Bs[p][row][ch << 3]);
  };

  const int nt = K >> 5;  // 64 K-tiles of 32

  // prologue: tile 0 -> slot 0, tile 1 -> slot 1 (tile-grouped issue order)
#pragma unroll
  for (int i = 0; i < 2; ++i) stageA(0, 0, i);
#pragma unroll
  for (int i = 0; i < 2; ++i) stageB(0, 0, i);
#pragma unroll
  for (int i = 0; i < 2; ++i) stageA(1, 1, i);
#pragma unroll
  for (int i = 0; i < 2; ++i) stageB(1, 1, i);

#pragma unroll 1
  for (int t = 0; t < nt; ++t) {
    const int sl = t % 3;
    if (t + 1 < nt) {
      asm volatile("s_waitcnt vmcnt(4)" ::: "memory");  // tile t landed; t+1 in flight
    } else {
      asm volatile("s_waitcnt vmcnt(0)" ::: "memory");  // last tile only
    }
    block_bar();

    const bool pf = (t + 2 < nt);
    const int s2 = pf ? (t + 2) % 3 : 0;

    bf16x8 bfr[4], afr[4];
    // ---- phase 0: mf 0-3; stage A of tile t+2 ----
#pragma unroll
    for (int n = 0; n < 4; ++n) bfr[n] = bfrag(sl, n);
#pragma unroll
    for (int j = 0; j < 4; ++j) afr[j] = afrag(sl, j);
    if (pf) { stageA(s2, t + 2, 0); stageA(s2, t + 2, 1); }
    __builtin_amdgcn_s_setprio(1);
#pragma unroll
    for (int j = 0; j < 4; ++j)
#pragma unroll
      for (int n = 0; n < 4; ++n) acc[j][n] = MFMA16(afr[j], bfr[n], acc[j][n]);
    __builtin_amdgcn_s_setprio(0);

    // ---- phase 1: mf 4-7; stage B of tile t+2 ----
#pragma unroll
    for (int j = 0; j < 4; ++j) afr[j] = afrag(sl, 4 + j);
    if (pf) { stageB(s2, t + 2, 0); stageB(s2, t + 2, 1); }
    __builtin_amdgcn_s_setprio(1);
#pragma unroll
    for (int j = 0; j < 4; ++j)
#pragma unroll
      for (int n = 0; n < 4; ++n) acc[4 + j][n] = MFMA16(afr[j], bfr[n], acc[4 + j][n]);
    __builtin_amdgcn_s_setprio(0);
    block_bar();  // all waves done reading slot sl (protects it from t+3's stage)
  }

  // epilogue: scatter to Q (scaled), K, V^T
  const int which = bn >> 11;  // uniform per block (2048 % 256 == 0)
#pragma unroll
  for (int mf = 0; mf < 8; ++mf)
#pragma unroll
    for (int nf = 0; nf < 4; ++nf)
#pragma unroll
      for (int r = 0; r < 4; ++r) {
        int m = bm + wm * 128 + mf * 16 + l4 * 4 + r;
        int n = bn + wn * 64 + nf * 16 + l15;
        float v = acc[mf][nf][r] + bias[n];
        int b = m >> 11, s = m & 2047;
        int d = n & 127;
        int head = (n & 2047) >> 7;
        size_t hb = (size_t)(b * 16 + head);
        if (which == 0) {
          v *= 0.08838834764831845f;  // 1/sqrt(128)
          qb[(hb * 2048 + s) * 128 + d] = (bf16_t)v;
        } else if (which == 1) {
          kb[(hb * 2048 + s) * 128 + d] = (bf16_t)v;
        } else {
          vtb[(hb * 128 + d) * 2048 + s] = (bf16_t)v;
        }
      }
}

// ---------------- bf16 GEMM, C = A * Bw^T (+bias fp32 out), 128x128 tile ----------------
// 2-phase counted-vmcnt double-buffer — dense projection.
__global__ __launch_bounds__(256) void gemm_bt_dense(
    const bf16_t* __restrict__ A, const bf16_t* __restrict__ Bw,
    const float* __restrict__ bias, float* __restrict__ O,
    int M, int N, int K) {
  __shared__ __attribute__((aligned(16))) bf16_t As[2][128][32];
  __shared__ __attribute__((aligned(16))) bf16_t Bs[2][128][32];
  const int tid = threadIdx.x;
  const int lane = tid & 63, wave = tid >> 6;
  const int wr = (wave >> 1) * 64, wc = (wave & 1) * 64;
  const int l15 = lane & 15, l4 = lane >> 4;
  const int bm = blockIdx.y * 128, bn = blockIdx.x * 128;

  f32x4 acc[4][4];
#pragma unroll
  for (int i = 0; i < 4; ++i)
#pragma unroll
    for (int j = 0; j < 4; ++j)
#pragma unroll
      for (int r = 0; r < 4; ++r) acc[i][j][r] = 0.0f;

  const int r0 = tid >> 2;
  const int co = (tid & 3) * 8;
  const bf16_t* gA = A + (size_t)(bm + r0) * K + co;
  const bf16_t* gB = Bw + (size_t)(bn + r0) * K + co;

  const int nt = K >> 5;

  gload_lds16(gA, &As[0][r0][co]);
  gload_lds16(gA + (size_t)64 * K, &As[0][r0 + 64][co]);
  gload_lds16(gB, &Bs[0][r0][co]);
  gload_lds16(gB + (size_t)64 * K, &Bs[0][r0 + 64][co]);

#pragma unroll 1
  for (int t = 0; t < nt; ++t) {
    const int cb = t & 1;
    if (t + 1 < nt) {
      const int kk = (t + 1) << 5;
      const int nb = cb ^ 1;
      gload_lds16(gA + kk, &As[nb][r0][co]);
      gload_lds16(gA + kk + (size_t)64 * K, &As[nb][r0 + 64][co]);
      gload_lds16(gB + kk, &Bs[nb][r0][co]);
      gload_lds16(gB + kk + (size_t)64 * K, &Bs[nb][r0 + 64][co]);
      asm volatile("s_waitcnt vmcnt(4)" ::: "memory");
    } else {
      asm volatile("s_waitcnt vmcnt(0)" ::: "memory");
    }
    block_bar();
    bf16x8 a[4], b[4];
#pragma unroll
    for (int i = 0; i < 4; ++i) a[i] = *(const bf16x8*)(&As[cb][wr + i * 16 + l15][l4 * 8]);
#pragma unroll
    for (int j = 0; j < 4; ++j) b[j] = *(const bf16x8*)(&Bs[cb][wc + j * 16 + l15][l4 * 8]);
#pragma unroll
    for (int i = 0; i < 4; ++i)
#pragma unroll
      for (int j = 0; j < 4; ++j) acc[i][j] = MFMA16(a[i], b[j], acc[i][j]);
    block_bar();
  }

#pragma unroll
  for (int i = 0; i < 4; ++i)
#pragma unroll
    for (int j = 0; j < 4; ++j)
#pragma unroll
      for (int r = 0; r < 4; ++r) {
        int m = bm + wr + i * 16 + l4 * 4 + r;
        int n = bn + wc + j * 16 + l15;
        O[(size_t)m * N + n] = acc[i][j][r] + bias[n];
      }
}

// ---------------- causal flash attention (R5-verified) ----------------
__global__ __launch_bounds__(512) void attn_kernel(
    const bf16_t* __restrict__ qbuf, const bf16_t* __restrict__ kbuf,
    const bf16_t* __restrict__ vtbuf, bf16_t* __restrict__ ctx) {
  __shared__ __attribute__((aligned(16))) bf16_t Ks[2][64][128];
  __shared__ __attribute__((aligned(16))) bf16_t Vts[2][128][64];
  __shared__ __attribute__((aligned(16))) bf16_t Ps[8][16][64];

  const int tid = threadIdx.x, lane = tid & 63, w = tid >> 6;
  const int l15 = lane & 15, l4 = lane >> 4;
  const int hb = blockIdx.y;
  const size_t hoff = (size_t)hb * 2048 * 128;
  const bf16_t* qh = qbuf + hoff;
  const bf16_t* kh = kbuf + hoff;
  const bf16_t* vh = vtbuf + hoff;
  const int b = hb >> 4, head = hb & 15;

  const int kr0 = tid >> 4, ks0 = tid & 15;
  const int vr0 = tid >> 3, vs0 = tid & 7;

  int buf = 0;

#pragma unroll 1
  for (int phase = 0; phase < 2; ++phase) {
    const int qt = phase == 0 ? blockIdx.x : 15 - blockIdx.x;
    const int q0 = qt * 128;
    const int nt = 2 * qt + 2;

    bf16x8 qa[4];
#pragma unroll
    for (int ks = 0; ks < 4; ++ks)
      qa[ks] = *(const bf16x8*)(qh + (size_t)(q0 + w * 16 + l15) * 128 + ks * 32 + l4 * 8);

    f32x4 accO[8];
#pragma unroll
    for (int df = 0; df < 8; ++df)
#pragma unroll
      for (int r = 0; r < 4; ++r) accO[df][r] = 0.0f;
    float mrow[4], lrow[4];
#pragma unroll
    for (int r = 0; r < 4; ++r) { mrow[r] = -1e30f; lrow[r] = 0.0f; }

    {
      const int kv0 = 0;
#pragma unroll
      for (int it = 0; it < 2; ++it) {
        int row = kr0 + it * 32, sch = ks0 ^ (row & 7);
        gload_lds16(kh + (size_t)(kv0 + row) * 128 + sch * 8, &Ks[buf][row][ks0 * 8]);
      }
#pragma unroll
      for (int it = 0; it < 2; ++it) {
        int row = vr0 + it * 64, sch = vs0 ^ (row & 7);
        gload_lds16(vh + (size_t)row * 2048 + kv0 + sch * 8, &Vts[buf][row][vs0 * 8]);
      }
    }

#pragma unroll 1
    for (int t = 0; t < nt; ++t) {
      const int kv0 = t * 64;
      if (t + 1 < nt) {
        const int kvn = (t + 1) * 64;
        const int nb = buf ^ 1;
#pragma unroll
        for (int it = 0; it < 2; ++it) {
          int row = kr0 + it * 32, sch = ks0 ^ (row & 7);
          gload_lds16(kh + (size_t)(kvn + row) * 128 + sch * 8, &Ks[nb][row][ks0 * 8]);
        }
#pragma unroll
        for (int it = 0; it < 2; ++it) {
          int row = vr0 + it * 64, sch = vs0 ^ (row & 7);
          gload_lds16(vh + (size_t)row * 2048 + kvn + sch * 8, &Vts[nb][row][vs0 * 8]);
        }
        asm volatile("s_waitcnt vmcnt(4)" ::: "memory");
      } else {
        asm volatile("s_waitcnt vmcnt(0)" ::: "memory");
      }
      block_bar();

      const bool active = (kv0 <= q0 + w * 16 + 15);
      if (active) {
        f32x4 sc[4];
#pragma unroll
        for (int nf = 0; nf < 4; ++nf) {
#pragma unroll
          for (int r = 0; r < 4; ++r) sc[nf][r] = 0.0f;
          int row = nf * 16 + l15;
#pragma unroll
          for (int ks = 0; ks < 4; ++ks) {
            int ch = (ks * 4 + l4) ^ (row & 7);
            bf16x8 kf = *(const bf16x8*)(&Ks[buf][row][ch * 8]);
            sc[nf] = MFMA16(qa[ks], kf, sc[nf]);
          }
        }

        if (kv0 + 63 > q0 + w * 16) {
#pragma unroll
          for (int nf = 0; nf < 4; ++nf)
#pragma unroll
            for (int r = 0; r < 4; ++r) {
              int qi = q0 + w * 16 + l4 * 4 + r;
              int kv = kv0 + nf * 16 + l15;
              if (kv > qi) sc[nf][r] = -1e30f;
            }
        }

        float tmax[4];
#pragma unroll
        for (int r = 0; r < 4; ++r)
          tmax[r] = fmaxf(fmaxf(sc[0][r], sc[1][r]), fmaxf(sc[2][r], sc[3][r]));
#pragma unroll
        for (int msk = 1; msk <= 8; msk <<= 1)
#pragma unroll
          for (int r = 0; r < 4; ++r)
            tmax[r] = fmaxf(tmax[r], __shfl_xor(tmax[r], msk, 64));

        bool defer = __all(tmax[0] <= mrow[0] + 8.0f && tmax[1] <= mrow[1] + 8.0f &&
                           tmax[2] <= mrow[2] + 8.0f && tmax[3] <= mrow[3] + 8.0f);
        if (!defer) {
          float scl[4];
#pragma unroll
          for (int r = 0; r < 4; ++r) {
            float mn = fmaxf(mrow[r], tmax[r]);
            scl[r] = __expf(mrow[r] - mn);
            mrow[r] = mn;
            lrow[r] *= scl[r];
          }
#pragma unroll
          for (int df = 0; df < 8; ++df)
#pragma unroll
            for (int r = 0; r < 4; ++r) accO[df][r] *= scl[r];
        }

        float rsum[4];
#pragma unroll
        for (int r = 0; r < 4; ++r) {
          float s0 = 0.0f;
#pragma unroll
          for (int nf = 0; nf < 4; ++nf) {
            float p = __expf(sc[nf][r] - mrow[r]);
            sc[nf][r] = p;
            s0 += p;
          }
          rsum[r] = s0;
        }
#pragma unroll
        for (int msk = 1; msk <= 8; msk <<= 1)
#pragma unroll
          for (int r = 0; r < 4; ++r) rsum[r] += __shfl_xor(rsum[r], msk, 64);
#pragma unroll
        for (int r = 0; r < 4; ++r) lrow[r] += rsum[r];

#pragma unroll
        for (int nf = 0; nf < 4; ++nf)
#pragma unroll
          for (int r = 0; r < 4; ++r) {
            int qi = l4 * 4 + r;
            int kv = nf * 16 + l15;
            int ch = (kv >> 3) ^ (qi & 7);
            Ps[w][qi][ch * 8 + (kv & 7)] = (bf16_t)sc[nf][r];
          }

        bf16x8 pa[2];
#pragma unroll
        for (int k2 = 0; k2 < 2; ++k2) {
          int ch = (k2 * 4 + l4) ^ (l15 & 7);
          pa[k2] = *(const bf16x8*)(&Ps[w][l15][ch * 8]);
        }
#pragma unroll
        for (int df = 0; df < 8; ++df) {
          int row = df * 16 + l15;
#pragma unroll
          for (int k2 = 0; k2 < 2; ++k2) {
            int ch = (k2 * 4 + l4) ^ (row & 7);
            bf16x8 vf = *(const bf16x8*)(&Vts[buf][row][ch * 8]);
            accO[df] = MFMA16(pa[k2], vf, accO[df]);
          }
        }
      }
      block_bar();
      buf ^= 1;
    }

    float inv[4];
#pragma unroll
    for (int r = 0; r < 4; ++r) inv[r] = 1.0f / lrow[r];
#pragma unroll
    for (int df = 0; df < 8; ++df)
#pragma unroll
      for (int r = 0; r < 4; ++r) {
        int s = q0 + w * 16 + l4 * 4 + r;
        int col = head * 128 + df * 16 + l15;
        ctx[((size_t)(b * 2048 + s)) * 2048 + col] = (bf16_t)(accO[df][r] * inv[r]);
      }
  }
}

extern "C" void kernel_launch(void* const* d_in, const int* in_sizes, int n_in,
                              void* d_out, int out_size, void* d_ws, size_t ws_size,
                              hipStream_t stream) {
  const float* hs = (const float*)d_in[0];
  const float* w_qkv = (const float*)d_in[2];
  const float* b_qkv = (const float*)d_in[3];
  const float* w_dense = (const float*)d_in[4];
  const float* b_dense = (const float*)d_in[5];
  float* out = (float*)d_out;

  const size_t SZ_HS = (size_t)4096 * 2048;
  const size_t SZ_WQKV = (size_t)6144 * 2048;
  const size_t SZ_WD = (size_t)2048 * 2048;
  const size_t SZ_H = (size_t)32 * 2048 * 128;

  char* ws = (char*)d_ws;
  bf16_t* A_ = (bf16_t*)ws;
  bf16_t* B_ = (bf16_t*)(ws + 2 * SZ_HS);
  bf16_t* Q_ = (bf16_t*)(ws + 2 * (SZ_HS + SZ_WQKV));
  bf16_t* K_ = Q_ + SZ_H;
  bf16_t* V_ = K_ + SZ_H;

  cvt_f32_bf16<<<(int)(SZ_HS / 4 / 256), 256, 0, stream>>>(hs, A_, (int)(SZ_HS / 4));
  cvt_f32_bf16<<<(int)(SZ_WQKV / 4 / 256), 256, 0, stream>>>(w_qkv, B_, (int)(SZ_WQKV / 4));

  gemm_qkv_256<<<dim3(24, 16), 512, 0, stream>>>(A_, B_, b_qkv, Q_, K_, V_, 4096, 6144, 2048);

  cvt_f32_bf16<<<(int)(SZ_WD / 4 / 256), 256, 0, stream>>>(w_dense, A_, (int)(SZ_WD / 4));

  attn_kernel<<<dim3(8, 32), 512, 0, stream>>>(Q_, K_, V_, B_);

  gemm_bt_dense<<<dim3(16, 32), 256, 0, stream>>>(B_, A_, b_dense, out, 4096, 2048, 2048);
}